// Round 1
// baseline (715.690 us; speedup 1.0000x reference)
//
#include <hip/hip_runtime.h>
#include <hip/hip_bf16.h>
#include <cstdint>
#include <cstddef>

// Problem constants
#define B_   4
#define S_   2048
#define D_   1024
#define H_   16
#define HD_  64
#define FF_  4096
#define MTOT (B_*S_)   // 8192 rows

typedef __bf16 bf16;
typedef bf16  bf16x8 __attribute__((ext_vector_type(8)));
typedef bf16  bf16x4 __attribute__((ext_vector_type(4)));
typedef float f32x4  __attribute__((ext_vector_type(4)));

// ---------------------------------------------------------------------------
// async global -> LDS, 16B per lane. LDS dst must be wave-uniform base;
// HW writes base + lane*16. (learn_hip m97 pattern)
// ---------------------------------------------------------------------------
__device__ __forceinline__ void async16(const bf16* g, bf16* l) {
  __builtin_amdgcn_global_load_lds(
      (const __attribute__((address_space(1))) unsigned int*)g,
      (__attribute__((address_space(3))) unsigned int*)l,
      16, 0, 0);
}

// ---------------------------------------------------------------------------
// Weight cast+transpose: W (K x N) fp32 -> Wt (N x K) bf16
// ---------------------------------------------------------------------------
__global__ void wcast_t(const float* __restrict__ W, bf16* __restrict__ Wt,
                        int K, int N) {
  __shared__ float t[32][33];
  const int k0 = blockIdx.y * 32, n0 = blockIdx.x * 32;
  const int tx = threadIdx.x, ty = threadIdx.y;
#pragma unroll
  for (int r = ty; r < 32; r += 8)
    t[r][tx] = W[(size_t)(k0 + r) * N + n0 + tx];
  __syncthreads();
#pragma unroll
  for (int r = ty; r < 32; r += 8)
    Wt[(size_t)(n0 + r) * K + k0 + tx] = (bf16)t[tx][r];
}

// ---------------------------------------------------------------------------
// Fused (residual-add +) LayerNorm -> bf16.  One block per row, 256 thr.
// ---------------------------------------------------------------------------
__global__ void ln_fused(const float* __restrict__ xin, const float* __restrict__ res,
                         const float* __restrict__ gamma, const float* __restrict__ beta,
                         bf16* __restrict__ out) {
  const int row = blockIdx.x, tid = threadIdx.x;
  const int lane = tid & 63, w = tid >> 6;
  f32x4 v = *(const f32x4*)(xin + (size_t)row * D_ + tid * 4);
  if (res) {
    f32x4 r = *(const f32x4*)(res + (size_t)row * D_ + tid * 4);
    v += r;
  }
  float sum = v[0] + v[1] + v[2] + v[3];
  float sq  = v[0]*v[0] + v[1]*v[1] + v[2]*v[2] + v[3]*v[3];
#pragma unroll
  for (int d = 1; d < 64; d <<= 1) {
    sum += __shfl_xor(sum, d);
    sq  += __shfl_xor(sq, d);
  }
  __shared__ float red[8];
  if (lane == 0) { red[w] = sum; red[4 + w] = sq; }
  __syncthreads();
  sum = red[0] + red[1] + red[2] + red[3];
  sq  = red[4] + red[5] + red[6] + red[7];
  const float mu   = sum * (1.f / D_);
  const float rstd = rsqrtf(sq * (1.f / D_) - mu * mu + 1e-5f);
  f32x4 g  = *(const f32x4*)(gamma + tid * 4);
  f32x4 bt = *(const f32x4*)(beta  + tid * 4);
  bf16x4 ov;
#pragma unroll
  for (int j = 0; j < 4; j++)
    ov[j] = (bf16)((v[j] - mu) * rstd * g[j] + bt[j]);
  *(bf16x4*)(out + (size_t)row * D_ + tid * 4) = ov;
}

// ---------------------------------------------------------------------------
// GEMM C = A(MxK,bf16) * Bt(NxK,bf16)^T, 128x128 tile, BK=32, 4 waves.
// m97 structure: global_load_lds(16B) staging, 2 barriers / K-step.
// EPI: 0=q (bias, *0.125, bf16)  1=k (bias, bf16)  2=v (bias, bf16 -> Vt[B,H,HD,S])
//      3=ffn1 (bias, relu, bf16) 4=ffn2 (bias + f_bf residual, fp32)
// ---------------------------------------------------------------------------
template <int EPI>
__global__ void gemm_bt(const bf16* __restrict__ A, const bf16* __restrict__ Bt,
                        const float* __restrict__ bias, void* __restrict__ Cout,
                        const bf16* __restrict__ addf, int M, int N, int K) {
  __shared__ bf16 As[128 * 32];
  __shared__ bf16 Bs[128 * 32];
  const int tid = threadIdx.x;
  const int lane = tid & 63;
  const int w = tid >> 6;
  const int wm = w >> 1, wn = w & 1;
  const int bm = blockIdx.y * 128;
  const int bn = blockIdx.x * 128;
  const int rg = lane >> 4, rl = lane & 15;

  const bf16* ga = A  + (size_t)(bm + w * 16 + (lane >> 2)) * K + (lane & 3) * 8;
  const bf16* gb = Bt + (size_t)(bn + w * 16 + (lane >> 2)) * K + (lane & 3) * 8;
  bf16* la = As + w * 512;
  bf16* lb = Bs + w * 512;
  const size_t rowadv = (size_t)64 * K;

  f32x4 acc[4][4];
  const f32x4 z = {0.f, 0.f, 0.f, 0.f};
#pragma unroll
  for (int m = 0; m < 4; m++)
#pragma unroll
    for (int n = 0; n < 4; n++) acc[m][n] = z;

  for (int kt = 0; kt < K; kt += 32) {
    __syncthreads();              // previous iteration's ds_reads complete
    async16(ga,          la);
    async16(ga + rowadv, la + 2048);
    async16(gb,          lb);
    async16(gb + rowadv, lb + 2048);
    ga += 32; gb += 32;
    __syncthreads();              // drains vmcnt(0): staged tiles visible

    bf16x8 af[4], bfr[4];
#pragma unroll
    for (int m = 0; m < 4; m++)
      af[m] = *(const bf16x8*)(As + (wm * 64 + m * 16 + rl) * 32 + rg * 8);
#pragma unroll
    for (int n = 0; n < 4; n++)
      bfr[n] = *(const bf16x8*)(Bs + (wn * 64 + n * 16 + rl) * 32 + rg * 8);
#pragma unroll
    for (int m = 0; m < 4; m++)
#pragma unroll
      for (int n = 0; n < 4; n++)
        acc[m][n] = __builtin_amdgcn_mfma_f32_16x16x32_bf16(af[m], bfr[n], acc[m][n], 0, 0, 0);
  }

  // Epilogue. C/D layout: col = lane&15, row = (lane>>4)*4 + i   [m89/m91]
#pragma unroll
  for (int m = 0; m < 4; m++) {
    const int row0 = bm + wm * 64 + m * 16 + rg * 4;
#pragma unroll
    for (int n = 0; n < 4; n++) {
      const int col = bn + wn * 64 + n * 16 + rl;
      const float bb = bias[col];
#pragma unroll
      for (int i = 0; i < 4; i++) {
        const int row = row0 + i;
        float v = acc[m][n][i] + bb;
        if (EPI == 0) {
          ((bf16*)Cout)[(size_t)row * N + col] = (bf16)(v * 0.125f);
        } else if (EPI == 1) {
          ((bf16*)Cout)[(size_t)row * N + col] = (bf16)v;
        } else if (EPI == 2) {
          const int b = row >> 11, s = row & 2047;
          const int h = col >> 6,  hd = col & 63;
          ((bf16*)Cout)[(((size_t)(b * H_ + h) * HD_ + hd) << 11) + s] = (bf16)v;
        } else if (EPI == 3) {
          ((bf16*)Cout)[(size_t)row * N + col] = (bf16)fmaxf(v, 0.f);
        } else {
          ((float*)Cout)[(size_t)row * N + col] =
              v + (float)addf[(size_t)row * N + col];
        }
      }
    }
  }
}

// ---------------------------------------------------------------------------
// Flash attention. Grid (S/128, B*H), 256 thr. Wave w owns 32 q-rows.
// Q pre-scaled by 1/8.  K: (8192,1024) bf16;  Vt: (B*H, HD, S) bf16.
// Online softmax per row; P staged per-wave in padded LDS (no barriers:
// LDS ops from one wave are processed in order).
// ---------------------------------------------------------------------------
__global__ void attn_fwd(const bf16* __restrict__ Q, const bf16* __restrict__ Kb,
                         const bf16* __restrict__ Vt, float* __restrict__ O) {
  __shared__ bf16 Pl[4][32][72];   // per-wave P tile, padded stride 72
  const int tid = threadIdx.x, lane = tid & 63, w = tid >> 6;
  const int rg = lane >> 4, rl = lane & 15;
  const int bh = blockIdx.y, b = bh >> 4, h = bh & 15;
  const int q0 = blockIdx.x * 128 + w * 32;

  const bf16* qp = Q + ((size_t)b * S_ + q0) * D_ + h * HD_;
  const bf16* kp = Kb + (size_t)b * S_ * D_ + h * HD_;
  const bf16* vp = Vt + (size_t)bh * HD_ * S_;

  bf16x8 qf[2][2];
#pragma unroll
  for (int m = 0; m < 2; m++)
#pragma unroll
    for (int kc = 0; kc < 2; kc++)
      qf[m][kc] = *(const bf16x8*)(qp + (size_t)(m * 16 + rl) * D_ + kc * 32 + rg * 8);

  const f32x4 z = {0.f, 0.f, 0.f, 0.f};
  f32x4 o[2][4];
  float mr[2][4], lr[2][4];
#pragma unroll
  for (int m = 0; m < 2; m++)
#pragma unroll
    for (int n = 0; n < 4; n++) o[m][n] = z;
#pragma unroll
  for (int m = 0; m < 2; m++)
#pragma unroll
    for (int i = 0; i < 4; i++) { mr[m][i] = -1e30f; lr[m][i] = 0.f; }

  for (int t = 0; t < S_ / 64; ++t) {
    // ---- S = Q * K^T (scores, 32x64 per wave) ----
    f32x4 s[2][4];
#pragma unroll
    for (int m = 0; m < 2; m++)
#pragma unroll
      for (int n = 0; n < 4; n++) s[m][n] = z;
#pragma unroll
    for (int kc = 0; kc < 2; kc++)
#pragma unroll
      for (int n = 0; n < 4; n++) {
        bf16x8 kf = *(const bf16x8*)(kp + (size_t)(t * 64 + n * 16 + rl) * D_ + kc * 32 + rg * 8);
#pragma unroll
        for (int m = 0; m < 2; m++)
          s[m][n] = __builtin_amdgcn_mfma_f32_16x16x32_bf16(qf[m][kc], kf, s[m][n], 0, 0, 0);
      }
    // ---- online softmax (row = m*16 + rg*4 + i; reduce across 16 lanes) ----
#pragma unroll
    for (int m = 0; m < 2; m++)
#pragma unroll
      for (int i = 0; i < 4; i++) {
        float rmax = fmaxf(fmaxf(s[m][0][i], s[m][1][i]), fmaxf(s[m][2][i], s[m][3][i]));
        rmax = fmaxf(rmax, __shfl_xor(rmax, 1));
        rmax = fmaxf(rmax, __shfl_xor(rmax, 2));
        rmax = fmaxf(rmax, __shfl_xor(rmax, 4));
        rmax = fmaxf(rmax, __shfl_xor(rmax, 8));
        const float mnew = fmaxf(mr[m][i], rmax);
        const float corr = __expf(mr[m][i] - mnew);
        mr[m][i] = mnew;
        float ps = 0.f;
#pragma unroll
        for (int n = 0; n < 4; n++) {
          float p = __expf(s[m][n][i] - mnew);
          s[m][n][i] = p;
          ps += p;
        }
        ps += __shfl_xor(ps, 1);
        ps += __shfl_xor(ps, 2);
        ps += __shfl_xor(ps, 4);
        ps += __shfl_xor(ps, 8);
        lr[m][i] = lr[m][i] * corr + ps;
#pragma unroll
        for (int n = 0; n < 4; n++) o[m][n][i] *= corr;
      }
    // ---- stage P to per-wave LDS (A-operand layout for PV) ----
#pragma unroll
    for (int m = 0; m < 2; m++)
#pragma unroll
      for (int n = 0; n < 4; n++)
#pragma unroll
        for (int i = 0; i < 4; i++)
          Pl[w][m * 16 + rg * 4 + i][n * 16 + rl] = (bf16)s[m][n][i];
    // ---- O += P * V ----
    bf16x8 pf[2][2];
#pragma unroll
    for (int m = 0; m < 2; m++)
#pragma unroll
      for (int kc = 0; kc < 2; kc++)
        pf[m][kc] = *(const bf16x8*)(&Pl[w][m * 16 + rl][kc * 32 + rg * 8]);
#pragma unroll
    for (int kc = 0; kc < 2; kc++)
#pragma unroll
      for (int n = 0; n < 4; n++) {
        bf16x8 vf = *(const bf16x8*)(vp + (size_t)(n * 16 + rl) * S_ + t * 64 + kc * 32 + rg * 8);
#pragma unroll
        for (int m = 0; m < 2; m++)
          o[m][n] = __builtin_amdgcn_mfma_f32_16x16x32_bf16(pf[m][kc], vf, o[m][n], 0, 0, 0);
      }
  }
  // ---- normalize and write attn output (fp32) ----
#pragma unroll
  for (int m = 0; m < 2; m++)
#pragma unroll
    for (int i = 0; i < 4; i++) {
      const float inv = 1.f / lr[m][i];
      const size_t rowb = ((size_t)b * S_ + q0 + m * 16 + rg * 4 + i) * D_ + h * HD_;
#pragma unroll
      for (int n = 0; n < 4; n++)
        O[rowb + n * 16 + rl] = o[m][n][i] * inv;
    }
}

// ---------------------------------------------------------------------------
// Orchestration
// ---------------------------------------------------------------------------
extern "C" void kernel_launch(void* const* d_in, const int* in_sizes, int n_in,
                              void* d_out, int out_size, void* d_ws, size_t ws_size,
                              hipStream_t stream) {
  (void)in_sizes; (void)n_in; (void)out_size; (void)ws_size;
  const float* x   = (const float*)d_in[0];
  const float* Wq  = (const float*)d_in[1];
  const float* bq  = (const float*)d_in[2];
  const float* Wk  = (const float*)d_in[3];
  const float* bk  = (const float*)d_in[4];
  const float* Wv  = (const float*)d_in[5];
  const float* bv  = (const float*)d_in[6];
  const float* g1  = (const float*)d_in[7];
  const float* be1 = (const float*)d_in[8];
  const float* g2  = (const float*)d_in[9];
  const float* be2 = (const float*)d_in[10];
  const float* W1  = (const float*)d_in[11];
  const float* b1  = (const float*)d_in[12];
  const float* W2  = (const float*)d_in[13];
  const float* b2  = (const float*)d_in[14];
  float* out = (float*)d_out;

  // ws layout (bytes). Peak live = 134 MB; ff1 aliases [22M,86M) (h,q,k,vt dead).
  char* p = (char*)d_ws;
  const size_t MB = (size_t)1 << 20;
  bf16*  wqt = (bf16*)(p + 0 * MB);     // (1024,1024) bf16 (N,K)
  bf16*  wkt = (bf16*)(p + 2 * MB);
  bf16*  wvt = (bf16*)(p + 4 * MB);
  bf16*  w1t = (bf16*)(p + 6 * MB);     // (4096,1024)
  bf16*  w2t = (bf16*)(p + 14 * MB);    // (1024,4096)
  bf16*  hb  = (bf16*)(p + 22 * MB);    // LN1 out (8192,1024)
  bf16*  qb  = (bf16*)(p + 38 * MB);    // q * 1/8
  bf16*  kb  = (bf16*)(p + 54 * MB);
  bf16*  vt  = (bf16*)(p + 70 * MB);    // V^T (B,H,HD,S)
  float* at  = (float*)(p + 86 * MB);   // attn out fp32 (8192,1024)
  bf16*  fb  = (bf16*)(p + 118 * MB);   // LN2 out
  bf16*  ff1 = (bf16*)(p + 22 * MB);    // relu(f@W1+b1) (8192,4096), aliased

  const dim3 tb(32, 8);
  wcast_t<<<dim3(32, 32),  tb, 0, stream>>>(Wq, wqt, 1024, 1024);
  wcast_t<<<dim3(32, 32),  tb, 0, stream>>>(Wk, wkt, 1024, 1024);
  wcast_t<<<dim3(32, 32),  tb, 0, stream>>>(Wv, wvt, 1024, 1024);
  wcast_t<<<dim3(128, 32), tb, 0, stream>>>(W1, w1t, 1024, 4096);
  wcast_t<<<dim3(32, 128), tb, 0, stream>>>(W2, w2t, 4096, 1024);

  ln_fused<<<MTOT, 256, 0, stream>>>(x, nullptr, g1, be1, hb);

  gemm_bt<0><<<dim3(8, 64), 256, 0, stream>>>(hb, wqt, bq, qb, nullptr, MTOT, 1024, 1024);
  gemm_bt<1><<<dim3(8, 64), 256, 0, stream>>>(hb, wkt, bk, kb, nullptr, MTOT, 1024, 1024);
  gemm_bt<2><<<dim3(8, 64), 256, 0, stream>>>(hb, wvt, bv, vt, nullptr, MTOT, 1024, 1024);

  attn_fwd<<<dim3(16, 64), 256, 0, stream>>>(qb, kb, vt, at);

  ln_fused<<<MTOT, 256, 0, stream>>>(at, x, g2, be2, fb);

  gemm_bt<3><<<dim3(32, 64), 256, 0, stream>>>(fb, w1t, b1, ff1, nullptr, MTOT, 4096, 1024);
  gemm_bt<4><<<dim3(8, 64),  256, 0, stream>>>(ff1, w2t, b2, out, fb, MTOT, 1024, 4096);
}

// Round 2
// 687.929 us; speedup vs baseline: 1.0404x; 1.0404x over previous
//
#include <hip/hip_runtime.h>
#include <hip/hip_bf16.h>
#include <cstdint>
#include <cstddef>

// Problem constants
#define B_   4
#define S_   2048
#define D_   1024
#define H_   16
#define HD_  64
#define FF_  4096
#define MTOT (B_*S_)   // 8192 rows

typedef __bf16 bf16;
typedef bf16  bf16x8 __attribute__((ext_vector_type(8)));
typedef bf16  bf16x4 __attribute__((ext_vector_type(4)));
typedef float f32x4  __attribute__((ext_vector_type(4)));

#define LOG2E 1.44269504088896340736f

// ---------------------------------------------------------------------------
// async global -> LDS, 16B per lane. LDS dst must be wave-uniform base;
// HW writes base + lane*16. (learn_hip m97 pattern)
// ---------------------------------------------------------------------------
__device__ __forceinline__ void async16(const bf16* g, bf16* l) {
  __builtin_amdgcn_global_load_lds(
      (const __attribute__((address_space(1))) unsigned int*)g,
      (__attribute__((address_space(3))) unsigned int*)l,
      16, 0, 0);
}

// ---------------------------------------------------------------------------
// Weight cast+transpose: W (K x N) fp32 -> Wt (N x K) bf16
// ---------------------------------------------------------------------------
__global__ void wcast_t(const float* __restrict__ W, bf16* __restrict__ Wt,
                        int K, int N) {
  __shared__ float t[32][33];
  const int k0 = blockIdx.y * 32, n0 = blockIdx.x * 32;
  const int tx = threadIdx.x, ty = threadIdx.y;
#pragma unroll
  for (int r = ty; r < 32; r += 8)
    t[r][tx] = W[(size_t)(k0 + r) * N + n0 + tx];
  __syncthreads();
#pragma unroll
  for (int r = ty; r < 32; r += 8)
    Wt[(size_t)(n0 + r) * K + k0 + tx] = (bf16)t[tx][r];
}

// ---------------------------------------------------------------------------
// Fused (residual-add +) LayerNorm -> bf16.  One block per row, 256 thr.
// ---------------------------------------------------------------------------
__global__ void ln_fused(const float* __restrict__ xin, const float* __restrict__ res,
                         const float* __restrict__ gamma, const float* __restrict__ beta,
                         bf16* __restrict__ out) {
  const int row = blockIdx.x, tid = threadIdx.x;
  const int lane = tid & 63, w = tid >> 6;
  f32x4 v = *(const f32x4*)(xin + (size_t)row * D_ + tid * 4);
  if (res) {
    f32x4 r = *(const f32x4*)(res + (size_t)row * D_ + tid * 4);
    v += r;
  }
  float sum = v[0] + v[1] + v[2] + v[3];
  float sq  = v[0]*v[0] + v[1]*v[1] + v[2]*v[2] + v[3]*v[3];
#pragma unroll
  for (int d = 1; d < 64; d <<= 1) {
    sum += __shfl_xor(sum, d);
    sq  += __shfl_xor(sq, d);
  }
  __shared__ float red[8];
  if (lane == 0) { red[w] = sum; red[4 + w] = sq; }
  __syncthreads();
  sum = red[0] + red[1] + red[2] + red[3];
  sq  = red[4] + red[5] + red[6] + red[7];
  const float mu   = sum * (1.f / D_);
  const float rstd = rsqrtf(sq * (1.f / D_) - mu * mu + 1e-5f);
  f32x4 g  = *(const f32x4*)(gamma + tid * 4);
  f32x4 bt = *(const f32x4*)(beta  + tid * 4);
  bf16x4 ov;
#pragma unroll
  for (int j = 0; j < 4; j++)
    ov[j] = (bf16)((v[j] - mu) * rstd * g[j] + bt[j]);
  *(bf16x4*)(out + (size_t)row * D_ + tid * 4) = ov;
}

// ---------------------------------------------------------------------------
// GEMM C = A(MxK,bf16) * Bt(NxK,bf16)^T, 128x128 tile, BK=32, 4 waves.
// m97 structure: global_load_lds(16B) staging, 2 barriers / K-step.
// EPI: 0=q (bias, *0.125*log2e, bf16)  1=k (bias, bf16)
//      2=v (bias, bf16 -> Vt[B,H,HD,S])
//      3=ffn1 (bias, relu, bf16) 4=ffn2 (bias + f_bf residual, fp32)
// ---------------------------------------------------------------------------
template <int EPI>
__global__ void gemm_bt(const bf16* __restrict__ A, const bf16* __restrict__ Bt,
                        const float* __restrict__ bias, void* __restrict__ Cout,
                        const bf16* __restrict__ addf, int M, int N, int K) {
  __shared__ bf16 As[128 * 32];
  __shared__ bf16 Bs[128 * 32];
  const int tid = threadIdx.x;
  const int lane = tid & 63;
  const int w = tid >> 6;
  const int wm = w >> 1, wn = w & 1;
  const int bm = blockIdx.y * 128;
  const int bn = blockIdx.x * 128;
  const int rg = lane >> 4, rl = lane & 15;

  const bf16* ga = A  + (size_t)(bm + w * 16 + (lane >> 2)) * K + (lane & 3) * 8;
  const bf16* gb = Bt + (size_t)(bn + w * 16 + (lane >> 2)) * K + (lane & 3) * 8;
  bf16* la = As + w * 512;
  bf16* lb = Bs + w * 512;
  const size_t rowadv = (size_t)64 * K;

  f32x4 acc[4][4];
  const f32x4 z = {0.f, 0.f, 0.f, 0.f};
#pragma unroll
  for (int m = 0; m < 4; m++)
#pragma unroll
    for (int n = 0; n < 4; n++) acc[m][n] = z;

  for (int kt = 0; kt < K; kt += 32) {
    __syncthreads();              // previous iteration's ds_reads complete
    async16(ga,          la);
    async16(ga + rowadv, la + 2048);
    async16(gb,          lb);
    async16(gb + rowadv, lb + 2048);
    ga += 32; gb += 32;
    __syncthreads();              // drains vmcnt(0): staged tiles visible

    bf16x8 af[4], bfr[4];
#pragma unroll
    for (int m = 0; m < 4; m++)
      af[m] = *(const bf16x8*)(As + (wm * 64 + m * 16 + rl) * 32 + rg * 8);
#pragma unroll
    for (int n = 0; n < 4; n++)
      bfr[n] = *(const bf16x8*)(Bs + (wn * 64 + n * 16 + rl) * 32 + rg * 8);
#pragma unroll
    for (int m = 0; m < 4; m++)
#pragma unroll
      for (int n = 0; n < 4; n++)
        acc[m][n] = __builtin_amdgcn_mfma_f32_16x16x32_bf16(af[m], bfr[n], acc[m][n], 0, 0, 0);
  }

  // Epilogue. C/D layout: col = lane&15, row = (lane>>4)*4 + i   [m89/m91]
#pragma unroll
  for (int m = 0; m < 4; m++) {
    const int row0 = bm + wm * 64 + m * 16 + rg * 4;
#pragma unroll
    for (int n = 0; n < 4; n++) {
      const int col = bn + wn * 64 + n * 16 + rl;
      const float bb = bias[col];
#pragma unroll
      for (int i = 0; i < 4; i++) {
        const int row = row0 + i;
        float v = acc[m][n][i] + bb;
        if (EPI == 0) {
          // fold 1/sqrt(HD) and log2(e) (softmax uses exp2) into Q
          ((bf16*)Cout)[(size_t)row * N + col] = (bf16)(v * (0.125f * LOG2E));
        } else if (EPI == 1) {
          ((bf16*)Cout)[(size_t)row * N + col] = (bf16)v;
        } else if (EPI == 2) {
          const int b = row >> 11, s = row & 2047;
          const int h = col >> 6,  hd = col & 63;
          ((bf16*)Cout)[(((size_t)(b * H_ + h) * HD_ + hd) << 11) + s] = (bf16)v;
        } else if (EPI == 3) {
          ((bf16*)Cout)[(size_t)row * N + col] = (bf16)fmaxf(v, 0.f);
        } else {
          ((float*)Cout)[(size_t)row * N + col] =
              v + (float)addf[(size_t)row * N + col];
        }
      }
    }
  }
}

// ---------------------------------------------------------------------------
// Flash attention. Grid (S/128, B*H), 256 thr. Wave w owns 32 q-rows.
// Q pre-scaled by log2e/8 (softmax in exp2 domain).
// K: (8192,1024) bf16;  Vt: (B*H, HD, S) bf16.
//
// K/V 64x64 tiles cooperatively staged to LDS via global_load_lds(16B),
// double-buffered, 2-phase schedule (T3 minimum recipe). LDS layout is
// XOR-swizzled (chunk ^= row&7, 16B chunks) applied on BOTH sides:
// pre-swizzled per-lane global source (rule #21) + swizzled ds_read —
// breaks the 16-way bank conflict of a row-major [64][64] bf16 tile.
// ---------------------------------------------------------------------------
__global__ void attn_fwd(const bf16* __restrict__ Q, const bf16* __restrict__ Kb,
                         const bf16* __restrict__ Vt, float* __restrict__ O) {
  __shared__ bf16 Ks[2][64 * 64];  // 8KB per buffer
  __shared__ bf16 Vs[2][64 * 64];
  __shared__ bf16 Pl[4][32][72];   // per-wave P tile, padded stride 72
  const int tid = threadIdx.x, lane = tid & 63, w = tid >> 6;
  const int rg = lane >> 4, rl = lane & 15;
  const int bh = blockIdx.y, b = bh >> 4, h = bh & 15;
  const int q0 = blockIdx.x * 128 + w * 32;

  const bf16* qp = Q + ((size_t)b * S_ + q0) * D_ + h * HD_;
  const bf16* kp = Kb + (size_t)b * S_ * D_ + h * HD_;
  const bf16* vp = Vt + (size_t)bh * HD_ * S_;

  // staging lane geometry: 8 rows x 8 chunks(16B) per issue, source-swizzled
  const int sr = lane >> 3;              // row within 8-row group
  const int sc = (lane & 7) ^ sr;        // swizzled 16B chunk in row

  // Wave w stages rows [w*16, w*16+16) of both tiles (2 issues per tensor).
#define STAGE(buf, t)                                                          \
  {                                                                            \
    const size_t tb = (size_t)((t) * 64);                                      \
    _Pragma("unroll")                                                          \
    for (int j = 0; j < 2; j++) {                                              \
      const int row = w * 16 + j * 8 + sr;                                     \
      async16(kp + (tb + row) * D_ + sc * 8, &Ks[buf][(w * 16 + j * 8) * 64]); \
      async16(vp + (size_t)row * S_ + tb + sc * 8,                             \
              &Vs[buf][(w * 16 + j * 8) * 64]);                                \
    }                                                                          \
  }

  bf16x8 qf[2][2];
#pragma unroll
  for (int m = 0; m < 2; m++)
#pragma unroll
    for (int kc = 0; kc < 2; kc++)
      qf[m][kc] = *(const bf16x8*)(qp + (size_t)(m * 16 + rl) * D_ + kc * 32 + rg * 8);

  const f32x4 z = {0.f, 0.f, 0.f, 0.f};
  f32x4 o[2][4];
  float mr[2][4], lr[2][4];
#pragma unroll
  for (int m = 0; m < 2; m++)
#pragma unroll
    for (int n = 0; n < 4; n++) o[m][n] = z;
#pragma unroll
  for (int m = 0; m < 2; m++)
#pragma unroll
    for (int i = 0; i < 4; i++) { mr[m][i] = -1e30f; lr[m][i] = 0.f; }

  STAGE(0, 0);
  __syncthreads();   // drains vmcnt(0): first tiles visible

  int cur = 0;
  for (int t = 0; t < S_ / 64; ++t) {
    if (t + 1 < S_ / 64) STAGE(cur ^ 1, t + 1);   // prefetch in flight
    const bf16* Kc = Ks[cur];
    const bf16* Vc = Vs[cur];

    // ---- S = Q * K^T (scores, 32x64 per wave) ----
    f32x4 s[2][4];
#pragma unroll
    for (int m = 0; m < 2; m++)
#pragma unroll
      for (int n = 0; n < 4; n++) s[m][n] = z;
#pragma unroll
    for (int kc = 0; kc < 2; kc++)
#pragma unroll
      for (int n = 0; n < 4; n++) {
        const int krow = n * 16 + rl;
        bf16x8 kf = *(const bf16x8*)(Kc + krow * 64 + (((kc * 4 + rg) ^ (krow & 7)) * 8));
#pragma unroll
        for (int m = 0; m < 2; m++)
          s[m][n] = __builtin_amdgcn_mfma_f32_16x16x32_bf16(qf[m][kc], kf, s[m][n], 0, 0, 0);
      }
    // ---- online softmax, exp2 domain (row = m*16 + rg*4 + i) ----
#pragma unroll
    for (int m = 0; m < 2; m++)
#pragma unroll
      for (int i = 0; i < 4; i++) {
        float rmax = fmaxf(fmaxf(s[m][0][i], s[m][1][i]), fmaxf(s[m][2][i], s[m][3][i]));
        rmax = fmaxf(rmax, __shfl_xor(rmax, 1));
        rmax = fmaxf(rmax, __shfl_xor(rmax, 2));
        rmax = fmaxf(rmax, __shfl_xor(rmax, 4));
        rmax = fmaxf(rmax, __shfl_xor(rmax, 8));
        const float mnew = fmaxf(mr[m][i], rmax);
        const float corr = __builtin_amdgcn_exp2f(mr[m][i] - mnew);
        mr[m][i] = mnew;
        float ps = 0.f;
#pragma unroll
        for (int n = 0; n < 4; n++) {
          float p = __builtin_amdgcn_exp2f(s[m][n][i] - mnew);
          s[m][n][i] = p;
          ps += p;
        }
        ps += __shfl_xor(ps, 1);
        ps += __shfl_xor(ps, 2);
        ps += __shfl_xor(ps, 4);
        ps += __shfl_xor(ps, 8);
        lr[m][i] = lr[m][i] * corr + ps;
#pragma unroll
        for (int n = 0; n < 4; n++) o[m][n][i] *= corr;
      }
    // ---- stage P to per-wave LDS (A-operand layout for PV) ----
#pragma unroll
    for (int m = 0; m < 2; m++)
#pragma unroll
      for (int n = 0; n < 4; n++)
#pragma unroll
        for (int i = 0; i < 4; i++)
          Pl[w][m * 16 + rg * 4 + i][n * 16 + rl] = (bf16)s[m][n][i];
    // ---- O += P * V ----
    bf16x8 pf[2][2];
#pragma unroll
    for (int m = 0; m < 2; m++)
#pragma unroll
      for (int kc = 0; kc < 2; kc++)
        pf[m][kc] = *(const bf16x8*)(&Pl[w][m * 16 + rl][kc * 32 + rg * 8]);
#pragma unroll
    for (int kc = 0; kc < 2; kc++)
#pragma unroll
      for (int n = 0; n < 4; n++) {
        const int vrow = n * 16 + rl;
        bf16x8 vf = *(const bf16x8*)(Vc + vrow * 64 + (((kc * 4 + rg) ^ (vrow & 7)) * 8));
#pragma unroll
        for (int m = 0; m < 2; m++)
          o[m][n] = __builtin_amdgcn_mfma_f32_16x16x32_bf16(pf[m][kc], vf, o[m][n], 0, 0, 0);
      }
    __syncthreads();   // drains vmcnt(0): prefetched tiles visible; buf reuse safe
    cur ^= 1;
  }
#undef STAGE
  // ---- normalize and write attn output (fp32) ----
#pragma unroll
  for (int m = 0; m < 2; m++)
#pragma unroll
    for (int i = 0; i < 4; i++) {
      const float inv = 1.f / lr[m][i];
      const size_t rowb = ((size_t)b * S_ + q0 + m * 16 + rg * 4 + i) * D_ + h * HD_;
#pragma unroll
      for (int n = 0; n < 4; n++)
        O[rowb + n * 16 + rl] = o[m][n][i] * inv;
    }
}

// ---------------------------------------------------------------------------
// Orchestration
// ---------------------------------------------------------------------------
extern "C" void kernel_launch(void* const* d_in, const int* in_sizes, int n_in,
                              void* d_out, int out_size, void* d_ws, size_t ws_size,
                              hipStream_t stream) {
  (void)in_sizes; (void)n_in; (void)out_size; (void)ws_size;
  const float* x   = (const float*)d_in[0];
  const float* Wq  = (const float*)d_in[1];
  const float* bq  = (const float*)d_in[2];
  const float* Wk  = (const float*)d_in[3];
  const float* bk  = (const float*)d_in[4];
  const float* Wv  = (const float*)d_in[5];
  const float* bv  = (const float*)d_in[6];
  const float* g1  = (const float*)d_in[7];
  const float* be1 = (const float*)d_in[8];
  const float* g2  = (const float*)d_in[9];
  const float* be2 = (const float*)d_in[10];
  const float* W1  = (const float*)d_in[11];
  const float* b1  = (const float*)d_in[12];
  const float* W2  = (const float*)d_in[13];
  const float* b2  = (const float*)d_in[14];
  float* out = (float*)d_out;

  // ws layout (bytes). Peak live = 134 MB; ff1 aliases [22M,86M) (h,q,k,vt dead).
  char* p = (char*)d_ws;
  const size_t MB = (size_t)1 << 20;
  bf16*  wqt = (bf16*)(p + 0 * MB);     // (1024,1024) bf16 (N,K)
  bf16*  wkt = (bf16*)(p + 2 * MB);
  bf16*  wvt = (bf16*)(p + 4 * MB);
  bf16*  w1t = (bf16*)(p + 6 * MB);     // (4096,1024)
  bf16*  w2t = (bf16*)(p + 14 * MB);    // (1024,4096)
  bf16*  hb  = (bf16*)(p + 22 * MB);    // LN1 out (8192,1024)
  bf16*  qb  = (bf16*)(p + 38 * MB);    // q * log2e/8
  bf16*  kb  = (bf16*)(p + 54 * MB);
  bf16*  vt  = (bf16*)(p + 70 * MB);    // V^T (B,H,HD,S)
  float* at  = (float*)(p + 86 * MB);   // attn out fp32 (8192,1024)
  bf16*  fb  = (bf16*)(p + 118 * MB);   // LN2 out
  bf16*  ff1 = (bf16*)(p + 22 * MB);    // relu(f@W1+b1) (8192,4096), aliased

  const dim3 tb(32, 8);
  wcast_t<<<dim3(32, 32),  tb, 0, stream>>>(Wq, wqt, 1024, 1024);
  wcast_t<<<dim3(32, 32),  tb, 0, stream>>>(Wk, wkt, 1024, 1024);
  wcast_t<<<dim3(32, 32),  tb, 0, stream>>>(Wv, wvt, 1024, 1024);
  wcast_t<<<dim3(128, 32), tb, 0, stream>>>(W1, w1t, 1024, 4096);
  wcast_t<<<dim3(32, 128), tb, 0, stream>>>(W2, w2t, 4096, 1024);

  ln_fused<<<MTOT, 256, 0, stream>>>(x, nullptr, g1, be1, hb);

  gemm_bt<0><<<dim3(8, 64), 256, 0, stream>>>(hb, wqt, bq, qb, nullptr, MTOT, 1024, 1024);
  gemm_bt<1><<<dim3(8, 64), 256, 0, stream>>>(hb, wkt, bk, kb, nullptr, MTOT, 1024, 1024);
  gemm_bt<2><<<dim3(8, 64), 256, 0, stream>>>(hb, wvt, bv, vt, nullptr, MTOT, 1024, 1024);

  attn_fwd<<<dim3(16, 64), 256, 0, stream>>>(qb, kb, vt, at);

  ln_fused<<<MTOT, 256, 0, stream>>>(at, x, g2, be2, fb);

  gemm_bt<3><<<dim3(32, 64), 256, 0, stream>>>(fb, w1t, b1, ff1, nullptr, MTOT, 4096, 1024);
  gemm_bt<4><<<dim3(8, 64),  256, 0, stream>>>(ff1, w2t, b2, out, fb, MTOT, 1024, 4096);
}

// Round 3
// 663.716 us; speedup vs baseline: 1.0783x; 1.0365x over previous
//
#include <hip/hip_runtime.h>
#include <hip/hip_bf16.h>
#include <cstdint>
#include <cstddef>

// Problem constants
#define B_   4
#define S_   2048
#define D_   1024
#define H_   16
#define HD_  64
#define FF_  4096
#define MTOT (B_*S_)   // 8192 rows

typedef __bf16 bf16;
typedef bf16  bf16x8 __attribute__((ext_vector_type(8)));
typedef bf16  bf16x4 __attribute__((ext_vector_type(4)));
typedef float f32x4  __attribute__((ext_vector_type(4)));

#define LOG2E 1.44269504088896340736f

// ---------------------------------------------------------------------------
// async global -> LDS, 16B per lane. LDS dst must be wave-uniform base;
// HW writes base + lane*16. (learn_hip m97 pattern)
// ---------------------------------------------------------------------------
__device__ __forceinline__ void async16(const bf16* g, bf16* l) {
  __builtin_amdgcn_global_load_lds(
      (const __attribute__((address_space(1))) unsigned int*)g,
      (__attribute__((address_space(3))) unsigned int*)l,
      16, 0, 0);
}

// ---------------------------------------------------------------------------
// Weight cast+transpose: W (K x N) fp32 -> Wt (N x K) bf16
// ---------------------------------------------------------------------------
__global__ void wcast_t(const float* __restrict__ W, bf16* __restrict__ Wt,
                        int K, int N) {
  __shared__ float t[32][33];
  const int k0 = blockIdx.y * 32, n0 = blockIdx.x * 32;
  const int tx = threadIdx.x, ty = threadIdx.y;
#pragma unroll
  for (int r = ty; r < 32; r += 8)
    t[r][tx] = W[(size_t)(k0 + r) * N + n0 + tx];
  __syncthreads();
#pragma unroll
  for (int r = ty; r < 32; r += 8)
    Wt[(size_t)(n0 + r) * K + k0 + tx] = (bf16)t[tx][r];
}

// ---------------------------------------------------------------------------
// Fused (residual-add +) LayerNorm -> bf16.  One block per row, 256 thr.
// ---------------------------------------------------------------------------
__global__ void ln_fused(const float* __restrict__ xin, const float* __restrict__ res,
                         const float* __restrict__ gamma, const float* __restrict__ beta,
                         bf16* __restrict__ out) {
  const int row = blockIdx.x, tid = threadIdx.x;
  const int lane = tid & 63, w = tid >> 6;
  f32x4 v = *(const f32x4*)(xin + (size_t)row * D_ + tid * 4);
  if (res) {
    f32x4 r = *(const f32x4*)(res + (size_t)row * D_ + tid * 4);
    v += r;
  }
  float sum = v[0] + v[1] + v[2] + v[3];
  float sq  = v[0]*v[0] + v[1]*v[1] + v[2]*v[2] + v[3]*v[3];
#pragma unroll
  for (int d = 1; d < 64; d <<= 1) {
    sum += __shfl_xor(sum, d);
    sq  += __shfl_xor(sq, d);
  }
  __shared__ float red[8];
  if (lane == 0) { red[w] = sum; red[4 + w] = sq; }
  __syncthreads();
  sum = red[0] + red[1] + red[2] + red[3];
  sq  = red[4] + red[5] + red[6] + red[7];
  const float mu   = sum * (1.f / D_);
  const float rstd = rsqrtf(sq * (1.f / D_) - mu * mu + 1e-5f);
  f32x4 g  = *(const f32x4*)(gamma + tid * 4);
  f32x4 bt = *(const f32x4*)(beta  + tid * 4);
  bf16x4 ov;
#pragma unroll
  for (int j = 0; j < 4; j++)
    ov[j] = (bf16)((v[j] - mu) * rstd * g[j] + bt[j]);
  *(bf16x4*)(out + (size_t)row * D_ + tid * 4) = ov;
}

// ---------------------------------------------------------------------------
// GEMM C = A(MxK,bf16) * Bt(NxK,bf16)^T, 128x128 tile, BK=32, 4 waves.
// m97 structure: global_load_lds(16B) staging, 2 barriers / K-step.
// EPI: 3=ffn1 (bias, relu, bf16) 4=ffn2 (bias + f_bf residual, fp32)
// ---------------------------------------------------------------------------
template <int EPI>
__global__ void gemm_bt(const bf16* __restrict__ A, const bf16* __restrict__ Bt,
                        const float* __restrict__ bias, void* __restrict__ Cout,
                        const bf16* __restrict__ addf, int M, int N, int K) {
  __shared__ bf16 As[128 * 32];
  __shared__ bf16 Bs[128 * 32];
  const int tid = threadIdx.x;
  const int lane = tid & 63;
  const int w = tid >> 6;
  const int wm = w >> 1, wn = w & 1;
  const int bm = blockIdx.y * 128;
  const int bn = blockIdx.x * 128;
  const int rg = lane >> 4, rl = lane & 15;

  const bf16* ga = A  + (size_t)(bm + w * 16 + (lane >> 2)) * K + (lane & 3) * 8;
  const bf16* gb = Bt + (size_t)(bn + w * 16 + (lane >> 2)) * K + (lane & 3) * 8;
  bf16* la = As + w * 512;
  bf16* lb = Bs + w * 512;
  const size_t rowadv = (size_t)64 * K;

  f32x4 acc[4][4];
  const f32x4 z = {0.f, 0.f, 0.f, 0.f};
#pragma unroll
  for (int m = 0; m < 4; m++)
#pragma unroll
    for (int n = 0; n < 4; n++) acc[m][n] = z;

  for (int kt = 0; kt < K; kt += 32) {
    __syncthreads();
    async16(ga,          la);
    async16(ga + rowadv, la + 2048);
    async16(gb,          lb);
    async16(gb + rowadv, lb + 2048);
    ga += 32; gb += 32;
    __syncthreads();

    bf16x8 af[4], bfr[4];
#pragma unroll
    for (int m = 0; m < 4; m++)
      af[m] = *(const bf16x8*)(As + (wm * 64 + m * 16 + rl) * 32 + rg * 8);
#pragma unroll
    for (int n = 0; n < 4; n++)
      bfr[n] = *(const bf16x8*)(Bs + (wn * 64 + n * 16 + rl) * 32 + rg * 8);
#pragma unroll
    for (int m = 0; m < 4; m++)
#pragma unroll
      for (int n = 0; n < 4; n++)
        acc[m][n] = __builtin_amdgcn_mfma_f32_16x16x32_bf16(af[m], bfr[n], acc[m][n], 0, 0, 0);
  }

  // Epilogue. C/D layout: col = lane&15, row = (lane>>4)*4 + i   [m89/m91]
#pragma unroll
  for (int m = 0; m < 4; m++) {
    const int row0 = bm + wm * 64 + m * 16 + rg * 4;
#pragma unroll
    for (int n = 0; n < 4; n++) {
      const int col = bn + wn * 64 + n * 16 + rl;
      const float bb = bias[col];
#pragma unroll
      for (int i = 0; i < 4; i++) {
        const int row = row0 + i;
        float v = acc[m][n][i] + bb;
        if (EPI == 3) {
          ((bf16*)Cout)[(size_t)row * N + col] = (bf16)fmaxf(v, 0.f);
        } else {
          ((float*)Cout)[(size_t)row * N + col] =
              v + (float)addf[(size_t)row * N + col];
        }
      }
    }
  }
}

// ---------------------------------------------------------------------------
// Fused QKV GEMM: A (8192x1024) x Wqkv^T (3072x1024) -> q/k/vt with per-sector
// epilogue. Wq^T,Wk^T,Wv^T contiguous in ws. Sector uniform per block (bn%1024).
// ---------------------------------------------------------------------------
__global__ void gemm_qkv(const bf16* __restrict__ A, const bf16* __restrict__ Bt,
                         const float* __restrict__ bq, const float* __restrict__ bk,
                         const float* __restrict__ bv, bf16* __restrict__ qout,
                         bf16* __restrict__ kout, bf16* __restrict__ vtout) {
  const int K = 1024;
  __shared__ bf16 As[128 * 32];
  __shared__ bf16 Bs[128 * 32];
  const int tid = threadIdx.x;
  const int lane = tid & 63;
  const int w = tid >> 6;
  const int wm = w >> 1, wn = w & 1;
  const int bm = blockIdx.y * 128;
  const int bn = blockIdx.x * 128;
  const int rg = lane >> 4, rl = lane & 15;

  const bf16* ga = A  + (size_t)(bm + w * 16 + (lane >> 2)) * K + (lane & 3) * 8;
  const bf16* gb = Bt + (size_t)(bn + w * 16 + (lane >> 2)) * K + (lane & 3) * 8;
  bf16* la = As + w * 512;
  bf16* lb = Bs + w * 512;
  const size_t rowadv = (size_t)64 * K;

  f32x4 acc[4][4];
  const f32x4 z = {0.f, 0.f, 0.f, 0.f};
#pragma unroll
  for (int m = 0; m < 4; m++)
#pragma unroll
    for (int n = 0; n < 4; n++) acc[m][n] = z;

  for (int kt = 0; kt < K; kt += 32) {
    __syncthreads();
    async16(ga,          la);
    async16(ga + rowadv, la + 2048);
    async16(gb,          lb);
    async16(gb + rowadv, lb + 2048);
    ga += 32; gb += 32;
    __syncthreads();

    bf16x8 af[4], bfr[4];
#pragma unroll
    for (int m = 0; m < 4; m++)
      af[m] = *(const bf16x8*)(As + (wm * 64 + m * 16 + rl) * 32 + rg * 8);
#pragma unroll
    for (int n = 0; n < 4; n++)
      bfr[n] = *(const bf16x8*)(Bs + (wn * 64 + n * 16 + rl) * 32 + rg * 8);
#pragma unroll
    for (int m = 0; m < 4; m++)
#pragma unroll
      for (int n = 0; n < 4; n++)
        acc[m][n] = __builtin_amdgcn_mfma_f32_16x16x32_bf16(af[m], bfr[n], acc[m][n], 0, 0, 0);
  }

  const int sector = bn >> 10;   // 0=q 1=k 2=v, uniform per block
#pragma unroll
  for (int m = 0; m < 4; m++) {
    const int row0 = bm + wm * 64 + m * 16 + rg * 4;
#pragma unroll
    for (int n = 0; n < 4; n++) {
      const int col = bn + wn * 64 + n * 16 + rl;
      const int cl = col & 1023;
      const float bb = (sector == 0) ? bq[cl] : (sector == 1 ? bk[cl] : bv[cl]);
#pragma unroll
      for (int i = 0; i < 4; i++) {
        const int row = row0 + i;
        const float v = acc[m][n][i] + bb;
        if (sector == 0) {
          qout[(size_t)row * D_ + cl] = (bf16)(v * (0.125f * LOG2E));
        } else if (sector == 1) {
          kout[(size_t)row * D_ + cl] = (bf16)v;
        } else {
          const int b = row >> 11, s = row & 2047;
          const int h = cl >> 6, hd = cl & 63;
          vtout[(((size_t)(b * H_ + h) * HD_ + hd) << 11) + s] = (bf16)v;
        }
      }
    }
  }
}

// ---------------------------------------------------------------------------
// Flash attention, swapped-operand (m214 structure on 16x16x32 fragments).
// Grid (S/128, B*H), 256 thr, wave w owns 32 q-rows. No K/V LDS staging
// (L2/L3-resident; m169). Q pre-scaled by log2e/8; softmax in exp2 domain.
//
// S^T = mfma(K_frag, Q_frag): col = q = rl (lane-local row!), row-in-tile =
// kv = rg*4+i. Row reduce = in-lane tree + shfl_xor(16,32) — 8 shfls/iter
// total vs 64 in the non-swapped form. PV swapped: O^T = mfma(V^T_frag,
// P^T_frag). P^T crosses the rg-layout mismatch via per-wave padded LDS
// (8 x ds_write_b64, 4 x ds_read_b128; stride 72 keeps rows 16B-aligned).
// ---------------------------------------------------------------------------
__global__ __launch_bounds__(256, 4)
void attn_fwd(const bf16* __restrict__ Q, const bf16* __restrict__ Kb,
              const bf16* __restrict__ Vt, float* __restrict__ O) {
  __shared__ bf16 Pl[4][32][72];   // per-wave P^T as [q_local][kv], 18432 B
  const int tid = threadIdx.x, lane = tid & 63, w = tid >> 6;
  const int rg = lane >> 4, rl = lane & 15;
  const int bh = blockIdx.y, b = bh >> 4, h = bh & 15;
  const int q0 = blockIdx.x * 128 + w * 32;

  const bf16* qp = Q + ((size_t)b * S_ + q0) * D_ + h * HD_;
  const bf16* kp = Kb + (size_t)b * S_ * D_ + h * HD_;
  const bf16* vp = Vt + (size_t)bh * HD_ * S_;

  // Q fragments (B-operand: col=q=rl, k=rg*8+j) — persistent
  bf16x8 qf[2][2];
#pragma unroll
  for (int m = 0; m < 2; m++)
#pragma unroll
    for (int kc = 0; kc < 2; kc++)
      qf[m][kc] = *(const bf16x8*)(qp + (size_t)(m * 16 + rl) * D_ + kc * 32 + rg * 8);

  const f32x4 z = {0.f, 0.f, 0.f, 0.f};
  f32x4 o[2][4];                 // O^T: row=hd(rg*4+i) in tile np, col=q=rl in tile m
  float mr[2], lr[2];
#pragma unroll
  for (int m = 0; m < 2; m++) {
    mr[m] = -1e30f; lr[m] = 0.f;
#pragma unroll
    for (int np = 0; np < 4; np++) o[m][np] = z;
  }

  for (int t = 0; t < S_ / 64; ++t) {
    // ---- K fragments (A-operand: row=kv=rl, k=rg*8+j) ----
    const bf16* kt = kp + (size_t)t * 64 * D_;
    bf16x8 kf[4][2];
#pragma unroll
    for (int n = 0; n < 4; n++)
#pragma unroll
      for (int kc = 0; kc < 2; kc++)
        kf[n][kc] = *(const bf16x8*)(kt + (size_t)(n * 16 + rl) * D_ + kc * 32 + rg * 8);

    // ---- S^T = K x Q^T : s[m][n] holds S^T[kv=n*16+rg*4+i][q=m*16+rl] ----
    f32x4 s[2][4];
#pragma unroll
    for (int m = 0; m < 2; m++)
#pragma unroll
      for (int n = 0; n < 4; n++) s[m][n] = z;
#pragma unroll
    for (int kc = 0; kc < 2; kc++)
#pragma unroll
      for (int n = 0; n < 4; n++)
#pragma unroll
        for (int m = 0; m < 2; m++)
          s[m][n] = __builtin_amdgcn_mfma_f32_16x16x32_bf16(kf[n][kc], qf[m][kc], s[m][n], 0, 0, 0);

    // ---- V^T fragments issued early (A-operand: row=hd=rl, k=kv=rg*8+j) ----
    bf16x8 vf[4][2];
#pragma unroll
    for (int np = 0; np < 4; np++)
#pragma unroll
      for (int kc = 0; kc < 2; kc++)
        vf[np][kc] = *(const bf16x8*)(vp + (size_t)(np * 16 + rl) * S_ + t * 64 + kc * 32 + rg * 8);

    // ---- online softmax, per-lane q-row (exp2 domain) ----
#pragma unroll
    for (int m = 0; m < 2; m++) {
      float x0 = fmaxf(fmaxf(s[m][0][0], s[m][0][1]), fmaxf(s[m][0][2], s[m][0][3]));
      float x1 = fmaxf(fmaxf(s[m][1][0], s[m][1][1]), fmaxf(s[m][1][2], s[m][1][3]));
      float x2 = fmaxf(fmaxf(s[m][2][0], s[m][2][1]), fmaxf(s[m][2][2], s[m][2][3]));
      float x3 = fmaxf(fmaxf(s[m][3][0], s[m][3][1]), fmaxf(s[m][3][2], s[m][3][3]));
      float vmax = fmaxf(fmaxf(x0, x1), fmaxf(x2, x3));
      vmax = fmaxf(vmax, __shfl_xor(vmax, 16));
      vmax = fmaxf(vmax, __shfl_xor(vmax, 32));
      const float mnew = fmaxf(mr[m], vmax);
      const float corr = __builtin_amdgcn_exp2f(mr[m] - mnew);
      mr[m] = mnew;
      float ps = 0.f;
#pragma unroll
      for (int n = 0; n < 4; n++)
#pragma unroll
        for (int i = 0; i < 4; i++) {
          const float p = __builtin_amdgcn_exp2f(s[m][n][i] - mnew);
          s[m][n][i] = p;
          ps += p;
        }
      ps += __shfl_xor(ps, 16);
      ps += __shfl_xor(ps, 32);
      lr[m] = lr[m] * corr + ps;
#pragma unroll
      for (int np = 0; np < 4; np++)
#pragma unroll
        for (int i = 0; i < 4; i++) o[m][np][i] *= corr;
      // ---- stage P^T tile rows: lane holds kv=n*16+rg*4+i for q=m*16+rl ----
#pragma unroll
      for (int n = 0; n < 4; n++) {
        bf16x4 pv;
#pragma unroll
        for (int i = 0; i < 4; i++) pv[i] = (bf16)s[m][n][i];
        *(bf16x4*)&Pl[w][m * 16 + rl][n * 16 + rg * 4] = pv;
      }
    }

    // ---- P^T B-fragments (col=q=rl, k=kv=rg*8+j) ----
    bf16x8 pf[2][2];
#pragma unroll
    for (int m = 0; m < 2; m++)
#pragma unroll
      for (int kc = 0; kc < 2; kc++)
        pf[m][kc] = *(const bf16x8*)&Pl[w][m * 16 + rl][kc * 32 + rg * 8];

    // ---- O^T += V^T x P^T ----
#pragma unroll
    for (int kc = 0; kc < 2; kc++)
#pragma unroll
      for (int np = 0; np < 4; np++)
#pragma unroll
        for (int m = 0; m < 2; m++)
          o[m][np] = __builtin_amdgcn_mfma_f32_16x16x32_bf16(vf[np][kc], pf[m][kc], o[m][np], 0, 0, 0);
  }

  // ---- normalize, write O (fp32): row=q, 4 consecutive hd per store ----
#pragma unroll
  for (int m = 0; m < 2; m++) {
    const float inv = 1.f / lr[m];
    const size_t rowb = ((size_t)b * S_ + q0 + m * 16 + rl) * D_ + h * HD_;
#pragma unroll
    for (int np = 0; np < 4; np++) {
      f32x4 ov;
#pragma unroll
      for (int i = 0; i < 4; i++) ov[i] = o[m][np][i] * inv;
      *(f32x4*)(O + rowb + np * 16 + rg * 4) = ov;
    }
  }
}

// ---------------------------------------------------------------------------
// Orchestration
// ---------------------------------------------------------------------------
extern "C" void kernel_launch(void* const* d_in, const int* in_sizes, int n_in,
                              void* d_out, int out_size, void* d_ws, size_t ws_size,
                              hipStream_t stream) {
  (void)in_sizes; (void)n_in; (void)out_size; (void)ws_size;
  const float* x   = (const float*)d_in[0];
  const float* Wq  = (const float*)d_in[1];
  const float* bq  = (const float*)d_in[2];
  const float* Wk  = (const float*)d_in[3];
  const float* bk  = (const float*)d_in[4];
  const float* Wv  = (const float*)d_in[5];
  const float* bv  = (const float*)d_in[6];
  const float* g1  = (const float*)d_in[7];
  const float* be1 = (const float*)d_in[8];
  const float* g2  = (const float*)d_in[9];
  const float* be2 = (const float*)d_in[10];
  const float* W1  = (const float*)d_in[11];
  const float* b1  = (const float*)d_in[12];
  const float* W2  = (const float*)d_in[13];
  const float* b2  = (const float*)d_in[14];
  float* out = (float*)d_out;

  // ws layout (bytes). wq/wk/wv transposed weights contiguous => fused QKV.
  char* p = (char*)d_ws;
  const size_t MB = (size_t)1 << 20;
  bf16*  wqkv = (bf16*)(p + 0 * MB);    // (3072,1024) bf16 (N,K), rows: Wq^T|Wk^T|Wv^T
  bf16*  w1t  = (bf16*)(p + 6 * MB);    // (4096,1024)
  bf16*  w2t  = (bf16*)(p + 14 * MB);   // (1024,4096)
  bf16*  hb   = (bf16*)(p + 22 * MB);   // LN1 out (8192,1024)
  bf16*  qb   = (bf16*)(p + 38 * MB);   // q * log2e/8
  bf16*  kb   = (bf16*)(p + 54 * MB);
  bf16*  vt   = (bf16*)(p + 70 * MB);   // V^T (B,H,HD,S)
  float* at   = (float*)(p + 86 * MB);  // attn out fp32 (8192,1024)
  bf16*  fb   = (bf16*)(p + 118 * MB);  // LN2 out
  bf16*  ff1  = (bf16*)(p + 22 * MB);   // relu(f@W1+b1) (8192,4096), aliased

  const dim3 tb(32, 8);
  wcast_t<<<dim3(32, 32),  tb, 0, stream>>>(Wq, wqkv,                1024, 1024);
  wcast_t<<<dim3(32, 32),  tb, 0, stream>>>(Wk, wqkv + 1024 * 1024,  1024, 1024);
  wcast_t<<<dim3(32, 32),  tb, 0, stream>>>(Wv, wqkv + 2048 * 1024,  1024, 1024);
  wcast_t<<<dim3(128, 32), tb, 0, stream>>>(W1, w1t, 1024, 4096);
  wcast_t<<<dim3(32, 128), tb, 0, stream>>>(W2, w2t, 4096, 1024);

  ln_fused<<<MTOT, 256, 0, stream>>>(x, nullptr, g1, be1, hb);

  gemm_qkv<<<dim3(24, 64), 256, 0, stream>>>(hb, wqkv, bq, bk, bv, qb, kb, vt);

  attn_fwd<<<dim3(16, 64), 256, 0, stream>>>(qb, kb, vt, at);

  ln_fused<<<MTOT, 256, 0, stream>>>(at, x, g2, be2, fb);

  gemm_bt<3><<<dim3(32, 64), 256, 0, stream>>>(fb, w1t, b1, ff1, nullptr, MTOT, 4096, 1024);
  gemm_bt<4><<<dim3(8, 64),  256, 0, stream>>>(ff1, w2t, b2, out, fb, MTOT, 1024, 4096);
}

// Round 4
// 544.765 us; speedup vs baseline: 1.3138x; 1.2184x over previous
//
#include <hip/hip_runtime.h>
#include <hip/hip_bf16.h>
#include <cstdint>
#include <cstddef>

// Problem constants
#define B_   4
#define S_   2048
#define D_   1024
#define H_   16
#define HD_  64
#define FF_  4096
#define MTOT (B_*S_)   // 8192 rows

typedef __bf16 bf16;
typedef bf16  bf16x8 __attribute__((ext_vector_type(8)));
typedef bf16  bf16x4 __attribute__((ext_vector_type(4)));
typedef float f32x4  __attribute__((ext_vector_type(4)));

#define LOG2E 1.44269504088896340736f

// ---------------------------------------------------------------------------
// async global -> LDS, 16B per lane. LDS dst must be wave-uniform base;
// HW writes base + lane*16. (learn_hip m97 pattern)
// ---------------------------------------------------------------------------
__device__ __forceinline__ void async16(const bf16* g, bf16* l) {
  __builtin_amdgcn_global_load_lds(
      (const __attribute__((address_space(1))) unsigned int*)g,
      (__attribute__((address_space(3))) unsigned int*)l,
      16, 0, 0);
}

// ---------------------------------------------------------------------------
// Weight cast+transpose: W (K x N) fp32 -> Wt (N x K) bf16
// ---------------------------------------------------------------------------
__global__ void wcast_t(const float* __restrict__ W, bf16* __restrict__ Wt,
                        int K, int N) {
  __shared__ float t[32][33];
  const int k0 = blockIdx.y * 32, n0 = blockIdx.x * 32;
  const int tx = threadIdx.x, ty = threadIdx.y;
#pragma unroll
  for (int r = ty; r < 32; r += 8)
    t[r][tx] = W[(size_t)(k0 + r) * N + n0 + tx];
  __syncthreads();
#pragma unroll
  for (int r = ty; r < 32; r += 8)
    Wt[(size_t)(n0 + r) * K + k0 + tx] = (bf16)t[tx][r];
}

// ---------------------------------------------------------------------------
// Fused (residual-add +) LayerNorm -> bf16.  One block per row, 256 thr.
// ---------------------------------------------------------------------------
__global__ void ln_fused(const float* __restrict__ xin, const float* __restrict__ res,
                         const float* __restrict__ gamma, const float* __restrict__ beta,
                         bf16* __restrict__ out) {
  const int row = blockIdx.x, tid = threadIdx.x;
  const int lane = tid & 63, w = tid >> 6;
  f32x4 v = *(const f32x4*)(xin + (size_t)row * D_ + tid * 4);
  if (res) {
    f32x4 r = *(const f32x4*)(res + (size_t)row * D_ + tid * 4);
    v += r;
  }
  float sum = v[0] + v[1] + v[2] + v[3];
  float sq  = v[0]*v[0] + v[1]*v[1] + v[2]*v[2] + v[3]*v[3];
#pragma unroll
  for (int d = 1; d < 64; d <<= 1) {
    sum += __shfl_xor(sum, d);
    sq  += __shfl_xor(sq, d);
  }
  __shared__ float red[8];
  if (lane == 0) { red[w] = sum; red[4 + w] = sq; }
  __syncthreads();
  sum = red[0] + red[1] + red[2] + red[3];
  sq  = red[4] + red[5] + red[6] + red[7];
  const float mu   = sum * (1.f / D_);
  const float rstd = rsqrtf(sq * (1.f / D_) - mu * mu + 1e-5f);
  f32x4 g  = *(const f32x4*)(gamma + tid * 4);
  f32x4 bt = *(const f32x4*)(beta  + tid * 4);
  bf16x4 ov;
#pragma unroll
  for (int j = 0; j < 4; j++)
    ov[j] = (bf16)((v[j] - mu) * rstd * g[j] + bt[j]);
  *(bf16x4*)(out + (size_t)row * D_ + tid * 4) = ov;
}

// ---------------------------------------------------------------------------
// GEMM C = A(MxK,bf16) * Bt(NxK,bf16)^T, 128x128 tile, BK=32, 4 waves.
// m97 structure: global_load_lds(16B) staging, 2 barriers / K-step.
// EPI: 3=ffn1 (bias, relu, bf16) 4=ffn2 (bias + f_bf residual, fp32)
// ---------------------------------------------------------------------------
template <int EPI>
__global__ void gemm_bt(const bf16* __restrict__ A, const bf16* __restrict__ Bt,
                        const float* __restrict__ bias, void* __restrict__ Cout,
                        const bf16* __restrict__ addf, int M, int N, int K) {
  __shared__ bf16 As[128 * 32];
  __shared__ bf16 Bs[128 * 32];
  const int tid = threadIdx.x;
  const int lane = tid & 63;
  const int w = tid >> 6;
  const int wm = w >> 1, wn = w & 1;
  const int bm = blockIdx.y * 128;
  const int bn = blockIdx.x * 128;
  const int rg = lane >> 4, rl = lane & 15;

  const bf16* ga = A  + (size_t)(bm + w * 16 + (lane >> 2)) * K + (lane & 3) * 8;
  const bf16* gb = Bt + (size_t)(bn + w * 16 + (lane >> 2)) * K + (lane & 3) * 8;
  bf16* la = As + w * 512;
  bf16* lb = Bs + w * 512;
  const size_t rowadv = (size_t)64 * K;

  f32x4 acc[4][4];
  const f32x4 z = {0.f, 0.f, 0.f, 0.f};
#pragma unroll
  for (int m = 0; m < 4; m++)
#pragma unroll
    for (int n = 0; n < 4; n++) acc[m][n] = z;

  for (int kt = 0; kt < K; kt += 32) {
    __syncthreads();
    async16(ga,          la);
    async16(ga + rowadv, la + 2048);
    async16(gb,          lb);
    async16(gb + rowadv, lb + 2048);
    ga += 32; gb += 32;
    __syncthreads();

    bf16x8 af[4], bfr[4];
#pragma unroll
    for (int m = 0; m < 4; m++)
      af[m] = *(const bf16x8*)(As + (wm * 64 + m * 16 + rl) * 32 + rg * 8);
#pragma unroll
    for (int n = 0; n < 4; n++)
      bfr[n] = *(const bf16x8*)(Bs + (wn * 64 + n * 16 + rl) * 32 + rg * 8);
#pragma unroll
    for (int m = 0; m < 4; m++)
#pragma unroll
      for (int n = 0; n < 4; n++)
        acc[m][n] = __builtin_amdgcn_mfma_f32_16x16x32_bf16(af[m], bfr[n], acc[m][n], 0, 0, 0);
  }

  // Epilogue. C/D layout: col = lane&15, row = (lane>>4)*4 + i   [m89/m91]
#pragma unroll
  for (int m = 0; m < 4; m++) {
    const int row0 = bm + wm * 64 + m * 16 + rg * 4;
#pragma unroll
    for (int n = 0; n < 4; n++) {
      const int col = bn + wn * 64 + n * 16 + rl;
      const float bb = bias[col];
#pragma unroll
      for (int i = 0; i < 4; i++) {
        const int row = row0 + i;
        float v = acc[m][n][i] + bb;
        if (EPI == 3) {
          ((bf16*)Cout)[(size_t)row * N + col] = (bf16)fmaxf(v, 0.f);
        } else {
          ((float*)Cout)[(size_t)row * N + col] =
              v + (float)addf[(size_t)row * N + col];
        }
      }
    }
  }
}

// ---------------------------------------------------------------------------
// Fused QKV GEMM: A (8192x1024) x Wqkv^T (3072x1024) -> q/k/vt with per-sector
// epilogue. Wq^T,Wk^T,Wv^T contiguous in ws. Sector uniform per block (bn%1024).
// ---------------------------------------------------------------------------
__global__ void gemm_qkv(const bf16* __restrict__ A, const bf16* __restrict__ Bt,
                         const float* __restrict__ bq, const float* __restrict__ bk,
                         const float* __restrict__ bv, bf16* __restrict__ qout,
                         bf16* __restrict__ kout, bf16* __restrict__ vtout) {
  const int K = 1024;
  __shared__ bf16 As[128 * 32];
  __shared__ bf16 Bs[128 * 32];
  const int tid = threadIdx.x;
  const int lane = tid & 63;
  const int w = tid >> 6;
  const int wm = w >> 1, wn = w & 1;
  const int bm = blockIdx.y * 128;
  const int bn = blockIdx.x * 128;
  const int rg = lane >> 4, rl = lane & 15;

  const bf16* ga = A  + (size_t)(bm + w * 16 + (lane >> 2)) * K + (lane & 3) * 8;
  const bf16* gb = Bt + (size_t)(bn + w * 16 + (lane >> 2)) * K + (lane & 3) * 8;
  bf16* la = As + w * 512;
  bf16* lb = Bs + w * 512;
  const size_t rowadv = (size_t)64 * K;

  f32x4 acc[4][4];
  const f32x4 z = {0.f, 0.f, 0.f, 0.f};
#pragma unroll
  for (int m = 0; m < 4; m++)
#pragma unroll
    for (int n = 0; n < 4; n++) acc[m][n] = z;

  for (int kt = 0; kt < K; kt += 32) {
    __syncthreads();
    async16(ga,          la);
    async16(ga + rowadv, la + 2048);
    async16(gb,          lb);
    async16(gb + rowadv, lb + 2048);
    ga += 32; gb += 32;
    __syncthreads();

    bf16x8 af[4], bfr[4];
#pragma unroll
    for (int m = 0; m < 4; m++)
      af[m] = *(const bf16x8*)(As + (wm * 64 + m * 16 + rl) * 32 + rg * 8);
#pragma unroll
    for (int n = 0; n < 4; n++)
      bfr[n] = *(const bf16x8*)(Bs + (wn * 64 + n * 16 + rl) * 32 + rg * 8);
#pragma unroll
    for (int m = 0; m < 4; m++)
#pragma unroll
      for (int n = 0; n < 4; n++)
        acc[m][n] = __builtin_amdgcn_mfma_f32_16x16x32_bf16(af[m], bfr[n], acc[m][n], 0, 0, 0);
  }

  const int sector = bn >> 10;   // 0=q 1=k 2=v, uniform per block
#pragma unroll
  for (int m = 0; m < 4; m++) {
    const int row0 = bm + wm * 64 + m * 16 + rg * 4;
#pragma unroll
    for (int n = 0; n < 4; n++) {
      const int col = bn + wn * 64 + n * 16 + rl;
      const int cl = col & 1023;
      const float bb = (sector == 0) ? bq[cl] : (sector == 1 ? bk[cl] : bv[cl]);
#pragma unroll
      for (int i = 0; i < 4; i++) {
        const int row = row0 + i;
        const float v = acc[m][n][i] + bb;
        if (sector == 0) {
          qout[(size_t)row * D_ + cl] = (bf16)(v * (0.125f * LOG2E));
        } else if (sector == 1) {
          kout[(size_t)row * D_ + cl] = (bf16)v;
        } else {
          const int b = row >> 11, s = row & 2047;
          const int h = cl >> 6, hd = cl & 63;
          vtout[(((size_t)(b * H_ + h) * HD_ + hd) << 11) + s] = (bf16)v;
        }
      }
    }
  }
}

// ---------------------------------------------------------------------------
// Flash attention, swapped-operand, 8 waves / block (QBLK=256, 32 q-rows/wave).
// Grid (S/256, B*H) = (8,64) = 512 blocks = exactly 2 resident blocks/CU.
//
// K and V 64x64 tiles cooperatively staged to LDS via global_load_lds(16B),
// double-buffered, one barrier per KV tile (T3 2-phase: STAGE issued at loop
// top, consumed next iteration). 8 waves share each staged tile -> 8x less
// K/V fetch traffic than per-wave register loads, and staging DMA keeps
// global latency off the VGPR-starved critical path (round-3 diagnosis).
// XOR swizzle (16B chunk ^= row&7) applied on BOTH sides: pre-swizzled
// per-lane global source + swizzled ds_read (rule #21).
//
// S^T = mfma(K_frag, Q_frag): q = rl is lane-local -> softmax row-reduce is
// in-lane tree + shfl_xor(16,32). PV swapped: O^T = mfma(V^T_frag, P^T_frag);
// P^T crosses the rg-layout mismatch via per-wave padded LDS (stride 72).
// ---------------------------------------------------------------------------
__global__ __launch_bounds__(512, 4)
void attn_fwd(const bf16* __restrict__ Q, const bf16* __restrict__ Kb,
              const bf16* __restrict__ Vt, float* __restrict__ O) {
  __shared__ bf16 Ks[2][64 * 64];   // [kv][hd], 8KB per buf
  __shared__ bf16 Vs[2][64 * 64];   // [hd][kv], 8KB per buf
  __shared__ bf16 Pl[8][32][72];    // per-wave P^T [q_local][kv], 36KB
  const int tid = threadIdx.x, lane = tid & 63, w = tid >> 6;
  const int rg = lane >> 4, rl = lane & 15;
  const int bh = blockIdx.y, b = bh >> 4, h = bh & 15;
  const int q0 = blockIdx.x * 256 + w * 32;

  const bf16* qp = Q + ((size_t)b * S_ + q0) * D_ + h * HD_;
  const bf16* kp = Kb + (size_t)b * S_ * D_ + h * HD_;
  const bf16* vp = Vt + (size_t)bh * HD_ * S_;

  // staging lane geometry: wave w stages rows [w*8, w*8+8) of each tile.
  // 8 rows x 8 chunks(16B); source chunk pre-swizzled so LDS chunk c of row r
  // holds global chunk c^(r&7).
  const int sr = lane >> 3;            // row within the wave's 8-row group
  const int sc = (lane & 7) ^ sr;      // swizzled source 16B chunk

#define STAGE(buf, t)                                                          \
  {                                                                            \
    const int row = w * 8 + sr;                                                \
    async16(kp + (size_t)((t) * 64 + row) * D_ + sc * 8, &Ks[buf][w * 8 * 64]);\
    async16(vp + (size_t)row * S_ + (t) * 64 + sc * 8,  &Vs[buf][w * 8 * 64]); \
  }

  // Q fragments (B-operand: col=q=rl, k=rg*8+j) — persistent
  bf16x8 qf[2][2];
#pragma unroll
  for (int m = 0; m < 2; m++)
#pragma unroll
    for (int kc = 0; kc < 2; kc++)
      qf[m][kc] = *(const bf16x8*)(qp + (size_t)(m * 16 + rl) * D_ + kc * 32 + rg * 8);

  const f32x4 z = {0.f, 0.f, 0.f, 0.f};
  f32x4 o[2][4];                 // O^T: row=hd(rg*4+i) in tile np, col=q=rl in tile m
  float mr[2], lr[2];
#pragma unroll
  for (int m = 0; m < 2; m++) {
    mr[m] = -1e30f; lr[m] = 0.f;
#pragma unroll
    for (int np = 0; np < 4; np++) o[m][np] = z;
  }

  STAGE(0, 0);
  __syncthreads();               // vmcnt(0) drain: first tiles visible

  int cur = 0;
  for (int t = 0; t < S_ / 64; ++t) {
    if (t + 1 < S_ / 64) STAGE(cur ^ 1, t + 1);   // prefetch stays in flight
    const bf16* Kc = Ks[cur];
    const bf16* Vc = Vs[cur];

    // ---- K fragments from LDS (A-operand: row=kv=n*16+rl, k=rg*8+j) ----
    bf16x8 kf[4][2];
#pragma unroll
    for (int n = 0; n < 4; n++) {
      const int krow = n * 16 + rl;
#pragma unroll
      for (int kc = 0; kc < 2; kc++)
        kf[n][kc] = *(const bf16x8*)(Kc + krow * 64 + (((kc * 4 + rg) ^ (krow & 7)) * 8));
    }

    // ---- S^T = K x Q^T : s[m][n] holds S^T[kv=n*16+rg*4+i][q=m*16+rl] ----
    f32x4 s[2][4];
#pragma unroll
    for (int m = 0; m < 2; m++)
#pragma unroll
      for (int n = 0; n < 4; n++) s[m][n] = z;
#pragma unroll
    for (int kc = 0; kc < 2; kc++)
#pragma unroll
      for (int n = 0; n < 4; n++)
#pragma unroll
        for (int m = 0; m < 2; m++)
          s[m][n] = __builtin_amdgcn_mfma_f32_16x16x32_bf16(kf[n][kc], qf[m][kc], s[m][n], 0, 0, 0);

    // ---- online softmax, per-lane q-row (exp2 domain) ----
#pragma unroll
    for (int m = 0; m < 2; m++) {
      float x0 = fmaxf(fmaxf(s[m][0][0], s[m][0][1]), fmaxf(s[m][0][2], s[m][0][3]));
      float x1 = fmaxf(fmaxf(s[m][1][0], s[m][1][1]), fmaxf(s[m][1][2], s[m][1][3]));
      float x2 = fmaxf(fmaxf(s[m][2][0], s[m][2][1]), fmaxf(s[m][2][2], s[m][2][3]));
      float x3 = fmaxf(fmaxf(s[m][3][0], s[m][3][1]), fmaxf(s[m][3][2], s[m][3][3]));
      float vmax = fmaxf(fmaxf(x0, x1), fmaxf(x2, x3));
      vmax = fmaxf(vmax, __shfl_xor(vmax, 16));
      vmax = fmaxf(vmax, __shfl_xor(vmax, 32));
      const float mnew = fmaxf(mr[m], vmax);
      const float corr = __builtin_amdgcn_exp2f(mr[m] - mnew);
      mr[m] = mnew;
      float ps = 0.f;
#pragma unroll
      for (int n = 0; n < 4; n++)
#pragma unroll
        for (int i = 0; i < 4; i++) {
          const float p = __builtin_amdgcn_exp2f(s[m][n][i] - mnew);
          s[m][n][i] = p;
          ps += p;
        }
      ps += __shfl_xor(ps, 16);
      ps += __shfl_xor(ps, 32);
      lr[m] = lr[m] * corr + ps;
#pragma unroll
      for (int np = 0; np < 4; np++)
#pragma unroll
        for (int i = 0; i < 4; i++) o[m][np][i] *= corr;
      // ---- stage P^T rows: lane holds kv=n*16+rg*4+i for q=m*16+rl ----
#pragma unroll
      for (int n = 0; n < 4; n++) {
        bf16x4 pv;
#pragma unroll
        for (int i = 0; i < 4; i++) pv[i] = (bf16)s[m][n][i];
        *(bf16x4*)&Pl[w][m * 16 + rl][n * 16 + rg * 4] = pv;
      }
    }

    // ---- P^T B-fragments (col=q=rl, k=kv=rg*8+j) ----
    bf16x8 pf[2][2];
#pragma unroll
    for (int m = 0; m < 2; m++)
#pragma unroll
      for (int kc = 0; kc < 2; kc++)
        pf[m][kc] = *(const bf16x8*)&Pl[w][m * 16 + rl][kc * 32 + rg * 8];

    // ---- V^T fragments from LDS (A-operand: row=hd=np*16+rl, k=kv) ----
    bf16x8 vf[4][2];
#pragma unroll
    for (int np = 0; np < 4; np++) {
      const int vrow = np * 16 + rl;
#pragma unroll
      for (int kc = 0; kc < 2; kc++)
        vf[np][kc] = *(const bf16x8*)(Vc + vrow * 64 + (((kc * 4 + rg) ^ (vrow & 7)) * 8));
    }

    // ---- O^T += V^T x P^T ----
#pragma unroll
    for (int kc = 0; kc < 2; kc++)
#pragma unroll
      for (int np = 0; np < 4; np++)
#pragma unroll
        for (int m = 0; m < 2; m++)
          o[m][np] = __builtin_amdgcn_mfma_f32_16x16x32_bf16(vf[np][kc], pf[m][kc], o[m][np], 0, 0, 0);

    __syncthreads();   // drains vmcnt(0)+lgkm: prefetched tiles ready, cur consumed
    cur ^= 1;
  }
#undef STAGE

  // ---- normalize, write O (fp32): row=q, 4 consecutive hd per store ----
#pragma unroll
  for (int m = 0; m < 2; m++) {
    const float inv = 1.f / lr[m];
    const size_t rowb = ((size_t)b * S_ + q0 + m * 16 + rl) * D_ + h * HD_;
#pragma unroll
    for (int np = 0; np < 4; np++) {
      f32x4 ov;
#pragma unroll
      for (int i = 0; i < 4; i++) ov[i] = o[m][np][i] * inv;
      *(f32x4*)(O + rowb + np * 16 + rg * 4) = ov;
    }
  }
}

// ---------------------------------------------------------------------------
// Orchestration
// ---------------------------------------------------------------------------
extern "C" void kernel_launch(void* const* d_in, const int* in_sizes, int n_in,
                              void* d_out, int out_size, void* d_ws, size_t ws_size,
                              hipStream_t stream) {
  (void)in_sizes; (void)n_in; (void)out_size; (void)ws_size;
  const float* x   = (const float*)d_in[0];
  const float* Wq  = (const float*)d_in[1];
  const float* bq  = (const float*)d_in[2];
  const float* Wk  = (const float*)d_in[3];
  const float* bk  = (const float*)d_in[4];
  const float* Wv  = (const float*)d_in[5];
  const float* bv  = (const float*)d_in[6];
  const float* g1  = (const float*)d_in[7];
  const float* be1 = (const float*)d_in[8];
  const float* g2  = (const float*)d_in[9];
  const float* be2 = (const float*)d_in[10];
  const float* W1  = (const float*)d_in[11];
  const float* b1  = (const float*)d_in[12];
  const float* W2  = (const float*)d_in[13];
  const float* b2  = (const float*)d_in[14];
  float* out = (float*)d_out;

  // ws layout (bytes). wq/wk/wv transposed weights contiguous => fused QKV.
  char* p = (char*)d_ws;
  const size_t MB = (size_t)1 << 20;
  bf16*  wqkv = (bf16*)(p + 0 * MB);    // (3072,1024) bf16 (N,K), rows: Wq^T|Wk^T|Wv^T
  bf16*  w1t  = (bf16*)(p + 6 * MB);    // (4096,1024)
  bf16*  w2t  = (bf16*)(p + 14 * MB);   // (1024,4096)
  bf16*  hb   = (bf16*)(p + 22 * MB);   // LN1 out (8192,1024)
  bf16*  qb   = (bf16*)(p + 38 * MB);   // q * log2e/8
  bf16*  kb   = (bf16*)(p + 54 * MB);
  bf16*  vt   = (bf16*)(p + 70 * MB);   // V^T (B,H,HD,S)
  float* at   = (float*)(p + 86 * MB);  // attn out fp32 (8192,1024)
  bf16*  fb   = (bf16*)(p + 118 * MB);  // LN2 out
  bf16*  ff1  = (bf16*)(p + 22 * MB);   // relu(f@W1+b1) (8192,4096), aliased

  const dim3 tb(32, 8);
  wcast_t<<<dim3(32, 32),  tb, 0, stream>>>(Wq, wqkv,                1024, 1024);
  wcast_t<<<dim3(32, 32),  tb, 0, stream>>>(Wk, wqkv + 1024 * 1024,  1024, 1024);
  wcast_t<<<dim3(32, 32),  tb, 0, stream>>>(Wv, wqkv + 2048 * 1024,  1024, 1024);
  wcast_t<<<dim3(128, 32), tb, 0, stream>>>(W1, w1t, 1024, 4096);
  wcast_t<<<dim3(32, 128), tb, 0, stream>>>(W2, w2t, 4096, 1024);

  ln_fused<<<MTOT, 256, 0, stream>>>(x, nullptr, g1, be1, hb);

  gemm_qkv<<<dim3(24, 64), 256, 0, stream>>>(hb, wqkv, bq, bk, bv, qb, kb, vt);

  attn_fwd<<<dim3(8, 64), 512, 0, stream>>>(qb, kb, vt, at);

  ln_fused<<<MTOT, 256, 0, stream>>>(at, x, g2, be2, fb);

  gemm_bt<3><<<dim3(32, 64), 256, 0, stream>>>(fb, w1t, b1, ff1, nullptr, MTOT, 4096, 1024);
  gemm_bt<4><<<dim3(8, 64),  256, 0, stream>>>(ff1, w2t, b2, out, fb, MTOT, 1024, 4096);
}